// Round 4
// baseline (63.280 us; speedup 1.0000x reference)
//
#include <hip/hip_runtime.h>
#include <math.h>

// Fully fused Preisach hysteresis.
// Per block: build the 2D prefix-sum density table C in LDS (redundantly per
// block -- parallel across blocks, so no wall-clock cost), then 16 waves each
// compute one output t via an exact backward-record scan with a parallel
// chunk filter (per-chunk up-move-max / down-move-min + lane suffix scan).
//
// Table: C[a][b] = sum_{alpha_idx<a, beta_idx<b, beta<=alpha} softplus(raw),
// a in [0,L], b in [0,L], stored row-major with stride SP=202 (float2 align).

__device__ __forceinline__ float softplus_f(float x) {
    return fmaxf(x, 0.0f) + log1pf(expf(-fabsf(x)));
}

__global__ __launch_bounds__(1024) void hyst_fused(
    const float* __restrict__ h,
    const float* __restrict__ mesh,
    const float* __restrict__ raw,
    const float* __restrict__ scale,
    const float* __restrict__ offset,
    float* __restrict__ out,
    int T, int L, int n)
{
    extern __shared__ float smem[];
    const int W  = L + 1;            // 201
    const int SP = (W + 1) & ~1;     // 202 even stride
    const int nc = (T + 63) >> 6;    // 64 chunks

    float* S     = smem;             // W * SP floats
    float* umaxs = smem + W * SP;    // nc
    float* dmins = umaxs + nc;       // nc

    const int tid  = threadIdx.x;
    const int lane = tid & 63;
    const int wid  = tid >> 6;
    const int nwv  = blockDim.x >> 6;    // 16
    const int r16  = lane & 15;
    const int seg  = lane >> 4;          // 0..3

    // ---- per-chunk up-move max / down-move min ----
    for (int c = wid; c < nc; c += nwv) {
        const int i = (c << 6) + lane;
        const bool inb = (i < T);
        const float hv = inb ? h[i] : 0.0f;
        const float hp = (inb && i > 0) ? h[i - 1] : 0.0f;
        float mu = (inb && hv > hp) ? hv : -1.0f;
        float md = (inb && hv < hp) ? hv : 2.0f;
        for (int o = 1; o < 64; o <<= 1) {
            mu = fmaxf(mu, __shfl_xor(mu, o));
            md = fminf(md, __shfl_xor(md, o));
        }
        if (lane == 0) { umaxs[c] = mu; dmins[c] = md; }
    }

    // ---- zero table ----
    {
        float2* S2 = (float2*)S;
        const int tot2 = (W * SP) >> 1;  // even
        for (int k = tid; k < tot2; k += blockDim.x) S2[k] = make_float2(0.f, 0.f);
    }
    __syncthreads();

    // ---- fill softplus(raw[p]) at S[(j+1)*SP + (i+1)] (coalesced raw) ----
    for (int p = tid; p < n; p += blockDim.x) {
        const float disc = (float)((2 * L + 1) * (2 * L + 1)) - 8.0f * (float)p;
        int i = (int)(((float)(2 * L + 1) - sqrtf(disc)) * 0.5f);
        i = max(0, min(i, L - 1));
        while (i + 1 <= L - 1 && ((i + 1) * (2 * L + 1 - (i + 1))) / 2 <= p) ++i;
        while (i > 0 && (i * (2 * L + 1 - i)) / 2 > p) --i;
        const int j = i + (p - (i * (2 * L + 1 - i)) / 2);
        S[(j + 1) * SP + (i + 1)] = softplus_f(raw[p]);
    }
    __syncthreads();

    // ---- row prefix over b (16 rows x 4 segs of 52 cols per wave) ----
    {
        const int a  = wid * 16 + r16;      // row 0..255, active a<=L
        const int b0 = seg * 52;            // 0,52,104,156
        const bool act = (a <= L);
        float2 v[26];
        float ssum = 0.0f;
        if (act) {
#pragma unroll
            for (int k = 0; k < 26; ++k) {
                const int b = b0 + 2 * k;
                float2 t2 = (b < SP) ? *(const float2*)&S[a * SP + b]
                                     : make_float2(0.f, 0.f);
                v[k] = t2;
                ssum += t2.x + t2.y;
            }
        }
        float excl = 0.0f;
#pragma unroll
        for (int k = 0; k < 3; ++k) {
            const float sk = __shfl(ssum, r16 + 16 * k);
            if (seg > k) excl += sk;
        }
        if (act) {
            float run = excl;
#pragma unroll
            for (int k = 0; k < 26; ++k) {
                const int b = b0 + 2 * k;
                if (b < SP) {
                    run += v[k].x; const float rx = run;
                    run += v[k].y; const float ry = run;
                    *(float2*)&S[a * SP + b] = make_float2(rx, ry);
                }
            }
        }
    }
    __syncthreads();

    // ---- column prefix over a: one float2 column-pair per 16-lane group,
    //      13 rows per lane (16*13 = 208 >= 201), shfl_up segmented scan ----
    {
        const int gid = wid * 4 + seg;      // 0..63 group id
        const int a0  = r16 * 13;           // first row this lane owns
        for (int cp = gid; cp < (SP >> 1); cp += 64) {
            const int b = 2 * cp;
            float2 v[13];
            float sx = 0.0f, sy = 0.0f;
#pragma unroll
            for (int k = 0; k < 13; ++k) {
                const int a = a0 + k;
                float2 t2 = (a < W) ? *(const float2*)&S[a * SP + b]
                                    : make_float2(0.f, 0.f);
                v[k] = t2;
                sx += t2.x; sy += t2.y;
            }
            // exclusive scan of (sx,sy) across the 16-lane group
            float ix = sx, iy = sy;
            for (int o = 1; o < 16; o <<= 1) {
                const float tx = __shfl_up(ix, o);
                const float ty = __shfl_up(iy, o);
                if (r16 >= o) { ix += tx; iy += ty; }
            }
            float rx = ix - sx, ry = iy - sy;   // exclusive prefix
#pragma unroll
            for (int k = 0; k < 13; ++k) {
                const int a = a0 + k;
                if (a < W) {
                    rx += v[k].x; ry += v[k].y;
                    *(float2*)&S[a * SP + b] = make_float2(rx, ry);
                }
            }
        }
    }

    // xs levels into registers (lane holds levels lane, +64, +128, +192)
    float xsr[4];
#pragma unroll
    for (int k = 0; k < 4; ++k) {
        const int jj = lane + 64 * k;
        xsr[k] = (jj < L) ? mesh[2 * jj + 1] : 2.0f;  // 2.0 never matches
    }
    __syncthreads();

    // ---- main: one wave per t ----
    const int t = blockIdx.x * nwv + wid;
    if (t >= T) return;

    float u_max = -1.0f, d_min = 2.0f;
    int Acov = 0, Bcov = L;
    float splus = 0.0f, sminus = 0.0f;

    auto count_le = [&](float v) -> int {
        int c = (xsr[0] <= v) + (xsr[1] <= v) + (xsr[2] <= v) + (xsr[3] <= v);
        for (int o = 1; o < 64; o <<= 1) c += __shfl_xor(c, o);
        return c;
    };
    auto count_lt = [&](float v) -> int {
        int c = (xsr[0] < v) + (xsr[1] < v) + (xsr[2] < v) + (xsr[3] < v);
        for (int o = 1; o < 64; o <<= 1) c += __shfl_xor(c, o);
        return c;
    };
    auto process_chunk = [&](int c) {
        const int i = (c << 6) + lane;
        const int ic = (i < T) ? i : (T - 1);           // clamp (safety)
        const float hv = h[ic];
        const float hp = (ic > 0) ? h[ic - 1] : 0.0f;
        const bool valid = (i <= t);
        const bool isup = valid && (hv > hp);
        const bool isdn = valid && (hv < hp);
        unsigned long long mup = __ballot(isup && hv > u_max);
        unsigned long long mdn = __ballot(isdn && hv < d_min);
        unsigned long long m = mup | mdn;
        while (m) {
            const int rl = 63 - __builtin_clzll(m);   // largest i first
            const float v = __shfl(hv, rl);
            if ((mup >> rl) & 1ull) {
                u_max = v;
                const int lo = count_le(v);
                if (lo > Acov) {
                    splus += S[lo * SP + Bcov] - S[Acov * SP + Bcov];
                    Acov = lo;
                }
            } else {
                d_min = v;
                const int lo = count_lt(v);
                if (lo < Bcov) {
                    sminus += (S[L * SP + Bcov] - S[L * SP + lo])
                            - (S[Acov * SP + Bcov] - S[Acov * SP + lo]);
                    Bcov = lo;
                }
            }
            const unsigned long long below =
                (rl == 0) ? 0ull : ((1ull << rl) - 1ull);
            mup = __ballot(isup && hv > u_max) & below;
            mdn = __ballot(isdn && hv < d_min) & below;
            m = mup | mdn;
        }
    };

    const int ct = t >> 6;
    process_chunk(ct);  // partial top chunk, exact

    for (int g = (ct - 1) >> 6; g >= 0; --g) {   // ct==0 -> skipped
        if (Acov >= L || Bcov <= 0) break;
        const int cbase = g << 6;
        const int c = cbase + lane;
        const bool act = (c < ct);
        const float vu = act ? umaxs[c] : -1.0f;
        const float vd = act ? dmins[c] : 2.0f;
        // suffix scans over descending chunk order (higher lanes = later chunks)
        float su = vu, sd = vd;
        for (int o = 1; o < 64; o <<= 1) {
            su = fmaxf(su, __shfl_down(su, o));
            sd = fminf(sd, __shfl_down(sd, o));
        }
        float sue = __shfl_down(su, 1);
        float sde = __shfl_down(sd, 1);
        if (lane == 63) { sue = -1.0f; sde = 2.0f; }
        // exact: chunk contains a record iff its up-max/down-min beats
        // everything processed after it (seed state + in-group suffix)
        const bool enter = act && ((vu > fmaxf(u_max, sue)) ||
                                   (vd < fminf(d_min, sde)));
        unsigned long long em = __ballot(enter);
        while (em) {
            const int rl = 63 - __builtin_clzll(em);
            process_chunk(cbase + rl);
            em &= ~(1ull << rl);
            if (Acov >= L || Bcov <= 0) break;
        }
    }

    // leftover region keeps initial -1
    sminus += S[L * SP + Bcov] - S[Acov * SP + Bcov];

    const float mval = (splus - sminus) / (float)n;
    if (lane == 0) out[t] = scale[0] * mval + offset[0];
}

extern "C" void kernel_launch(void* const* d_in, const int* in_sizes, int n_in,
                              void* d_out, int out_size, void* d_ws, size_t ws_size,
                              hipStream_t stream) {
    const float* h      = (const float*)d_in[0];
    const float* mesh   = (const float*)d_in[1];
    const float* raw    = (const float*)d_in[2];
    const float* scale  = (const float*)d_in[3];
    const float* offset = (const float*)d_in[4];
    float* out = (float*)d_out;

    const int T = in_sizes[0];
    const int n = in_sizes[2];
    const int L = (int)((sqrt(8.0 * (double)n + 1.0) - 1.0) / 2.0 + 0.5);
    const int W = L + 1;
    const int SP = (W + 1) & ~1;
    const int nc = (T + 63) / 64;

    const size_t shmem = ((size_t)W * SP + 2 * (size_t)nc) * sizeof(float);
    // 162,920 B <= 163,840 B max group segment on gfx950
    (void)hipFuncSetAttribute(reinterpret_cast<const void*>(hyst_fused),
                              hipFuncAttributeMaxDynamicSharedMemorySize,
                              (int)shmem);

    const int nwv = 16;                       // 1024 threads = 16 waves
    const int grid = (T + nwv - 1) / nwv;     // 256 blocks -> 1/CU
    hipLaunchKernelGGL(hyst_fused, dim3(grid), dim3(1024), shmem, stream,
                       h, mesh, raw, scale, offset, out, T, L, n);
}